// Round 1
// baseline (113.058 us; speedup 1.0000x reference)
//
#include <hip/hip_runtime.h>

// Problem constants (from reference)
#define B_SZ   256
#define L_SZ   200
#define EMBED  128
#define MAX_G  8
#define NTOK   (B_SZ * L_SZ)        // 51200 tokens
#define F4_PER_ROW (EMBED / 4)      // 32 float4 per embedding row

// 32 lanes per token, each lane owns one float4 of the 128-float row.
// Block = 256 threads -> 8 tokens/block. Grid = 51200/8 = 6400 blocks.
__global__ __launch_bounds__(256) void bert_embed_kernel(
    const int*    __restrict__ seq,       // [B,L]
    const float4* __restrict__ tok_tab,   // [VOCAB, 32] (float4 view)
    const float4* __restrict__ gen_tab,   // [21, 32]
    const float4* __restrict__ pos_tab,   // [200, 32]
    const int*    __restrict__ tgid,      // [VOCAB, 8]
    const int*    __restrict__ gcnt,      // [VOCAB]
    float4*       __restrict__ out)       // [B,L,32]
{
    const int tid   = threadIdx.x;
    const int group = tid >> 5;          // token slot within block (0..7)
    const int lane  = tid & 31;          // float4 index within row (0..31)

    const int token_idx = blockIdx.x * 8 + group;   // 0..51199
    if (token_idx >= NTOK) return;

    const int l = token_idx % L_SZ;
    const int t = seq[token_idx];

    // token embedding row (512B contiguous gather per group)
    float4 acc = tok_tab[(long)t * F4_PER_ROW + lane];

    // positional embedding (L1-hot, 102 KB table)
    const float4 p = pos_tab[l * F4_PER_ROW + lane];
    acc.x += p.x; acc.y += p.y; acc.z += p.z; acc.w += p.w;

    // genre mean: up to 8 rows of the 10.75 KB genre table (L1-resident)
    const int cnt = gcnt[t];
    const int* g = tgid + (long)t * MAX_G;
    float4 gs; gs.x = 0.f; gs.y = 0.f; gs.z = 0.f; gs.w = 0.f;
    #pragma unroll 1
    for (int i = 0; i < cnt; ++i) {
        const int gid = g[i];
        const float4 ge = gen_tab[gid * F4_PER_ROW + lane];
        gs.x += ge.x; gs.y += ge.y; gs.z += ge.z; gs.w += ge.w;
    }
    const float inv = 1.0f / (float)cnt;
    acc.x += gs.x * inv; acc.y += gs.y * inv;
    acc.z += gs.z * inv; acc.w += gs.w * inv;

    out[(long)token_idx * F4_PER_ROW + lane] = acc;
}

extern "C" void kernel_launch(void* const* d_in, const int* in_sizes, int n_in,
                              void* d_out, int out_size, void* d_ws, size_t ws_size,
                              hipStream_t stream) {
    const int*    seq     = (const int*)   d_in[0];  // sequence (256,200) int32
    const float4* tok_tab = (const float4*)d_in[1];  // token_table (100000,128) f32
    const float4* gen_tab = (const float4*)d_in[2];  // genre_table (21,128) f32
    const float4* pos_tab = (const float4*)d_in[3];  // pos_table (200,128) f32
    const int*    tgid    = (const int*)   d_in[4];  // token_genre_ids (100000,8)
    const int*    gcnt    = (const int*)   d_in[5];  // genre_counts (100000,)
    float4*       out     = (float4*)      d_out;    // (256,200,128) f32

    const int blocks = (NTOK + 7) / 8;  // 6400
    bert_embed_kernel<<<blocks, 256, 0, stream>>>(seq, tok_tab, gen_tab,
                                                  pos_tab, tgid, gcnt, out);
}

// Round 3
// 111.042 us; speedup vs baseline: 1.0182x; 1.0182x over previous
//
#include <hip/hip_runtime.h>

// Problem constants (from reference)
#define B_SZ   256
#define L_SZ   200
#define EMBED  128
#define MAX_G  8
#define NTOK   (B_SZ * L_SZ)        // 51200 tokens
#define F4_PER_ROW (EMBED / 4)      // 32 float4 per embedding row

typedef float nativef4 __attribute__((ext_vector_type(4)));  // for nontemporal store

// 32 lanes per token, each lane owns one float4 of the 128-float row.
// Block = 256 threads -> 8 tokens/block. Grid = 51200/8 = 6400 blocks.
__global__ __launch_bounds__(256) void bert_embed_kernel(
    const int*    __restrict__ seq,       // [B,L]
    const float4* __restrict__ tok_tab,   // [VOCAB, 32] (float4 view)
    const float4* __restrict__ gen_tab,   // [21, 32]
    const float4* __restrict__ pos_tab,   // [200, 32]
    const int*    __restrict__ tgid,      // [VOCAB, 8]
    const int*    __restrict__ gcnt,      // [VOCAB]
    float4*       __restrict__ out)       // [B,L,32]
{
    const int tid   = threadIdx.x;
    const int group = tid >> 5;          // token slot within block (0..7)
    const int lane  = tid & 31;          // float4 index within row (0..31)

    const int token_idx = blockIdx.x * 8 + group;   // 0..51199
    if (token_idx >= NTOK) return;

    const int l = token_idx % L_SZ;
    const int t = seq[token_idx];

    // Issue all independent loads up front: token row, pos row, count, all 8 gids.
    const float4 tokv = tok_tab[(long)t * F4_PER_ROW + lane];
    const float4 p    = pos_tab[l * F4_PER_ROW + lane];
    const int    cnt  = gcnt[t];

    // 8 genre ids = 32B contiguous, always-valid memory (table is [VOCAB][8]).
    const int4* g4 = (const int4*)(tgid + (long)t * MAX_G);
    const int4  ga = g4[0];
    const int4  gb = g4[1];
    const int gid[MAX_G] = { ga.x, ga.y, ga.z, ga.w, gb.x, gb.y, gb.z, gb.w };

    // Issue all 8 genre-row loads independently (tiny 10.75KB table, L1-hot).
    float4 r[MAX_G];
    #pragma unroll
    for (int i = 0; i < MAX_G; ++i)
        r[i] = gen_tab[gid[i] * F4_PER_ROW + lane];

    // Masked mean: weight inv for i<cnt, 0 otherwise.
    const float inv = 1.0f / (float)cnt;
    nativef4 acc;
    acc.x = tokv.x + p.x;
    acc.y = tokv.y + p.y;
    acc.z = tokv.z + p.z;
    acc.w = tokv.w + p.w;
    #pragma unroll
    for (int i = 0; i < MAX_G; ++i) {
        const float w = (i < cnt) ? inv : 0.0f;
        acc.x = fmaf(w, r[i].x, acc.x);
        acc.y = fmaf(w, r[i].y, acc.y);
        acc.z = fmaf(w, r[i].z, acc.z);
        acc.w = fmaf(w, r[i].w, acc.w);
    }

    // Nontemporal store: output has zero reuse; keep L2 for the token gather.
    nativef4* dst = (nativef4*)&out[(long)token_idx * F4_PER_ROW + lane];
    __builtin_nontemporal_store(acc, dst);
}

extern "C" void kernel_launch(void* const* d_in, const int* in_sizes, int n_in,
                              void* d_out, int out_size, void* d_ws, size_t ws_size,
                              hipStream_t stream) {
    const int*    seq     = (const int*)   d_in[0];  // sequence (256,200) int32
    const float4* tok_tab = (const float4*)d_in[1];  // token_table (100000,128) f32
    const float4* gen_tab = (const float4*)d_in[2];  // genre_table (21,128) f32
    const float4* pos_tab = (const float4*)d_in[3];  // pos_table (200,128) f32
    const int*    tgid    = (const int*)   d_in[4];  // token_genre_ids (100000,8)
    const int*    gcnt    = (const int*)   d_in[5];  // genre_counts (100000,)
    float4*       out     = (float4*)      d_out;    // (256,200,128) f32

    const int blocks = (NTOK + 7) / 8;  // 6400
    bert_embed_kernel<<<blocks, 256, 0, stream>>>(seq, tok_tab, gen_tab,
                                                  pos_tab, tgid, gcnt, out);
}